// Round 4
// baseline (233.953 us; speedup 1.0000x reference)
//
#include <hip/hip_runtime.h>

#define NDIM 4096
#define B_LG 256
#define B_SM 256
#define N_WID 128
#define R_LG 64
#define R_SM 16
#define BLOCK 1024
#define MAXB 256          // bucket capacity per wid
#define TD 2048           // d-tile staged in LDS
#define MG 4              // max batches per pass over A

// d_ws layout (ints): [0..128) cnt_l | [128..256) cnt_s |
//   [256 .. 256+128*256) bucket_l | [+32768 ..) bucket_s
#define WS_CNT_L 0
#define WS_CNT_S 128
#define WS_BKT_L 256
#define WS_BKT_S (256 + N_WID * MAXB)

// ---------------- kernel 1: bucket batches by wid (single block) ------------
__global__ __launch_bounds__(256)
void bucket_kernel(const int* __restrict__ wids_l,
                   const int* __restrict__ wids_s,
                   int* __restrict__ ws)
{
    __shared__ int cl[N_WID], cs[N_WID];
    const int t = threadIdx.x;
    if (t < N_WID) { cl[t] = 0; cs[t] = 0; }
    __syncthreads();
    {
        const int w = wids_l[t];
        const int slot = atomicAdd(&cl[w], 1);
        ws[WS_BKT_L + w * MAXB + slot] = t;
    }
    {
        const int w = wids_s[t];
        const int slot = atomicAdd(&cs[w], 1);
        ws[WS_BKT_S + w * MAXB + slot] = t;
    }
    __syncthreads();
    if (t < N_WID) { ws[WS_CNT_L + t] = cl[t]; ws[WS_CNT_S + t] = cs[t]; }
}

// ---------------- kernel 2: grouped GEMV ------------------------------------
// One pass streams A[wid] once while computing up to MG batches' y = x·A.
// A is [NDIM][R] row-major. Thread t loads float4 at flat offset t*4 of each
// contiguous 16KB chunk -> perfectly coalesced. x rows staged in LDS tiles.
template<int R, int M>
__device__ __forceinline__ void gemv_group(
    const float* __restrict__ x,        // x rows base for this class
    const float* __restrict__ Ab,       // A[wid]
    float* __restrict__ outb,           // out base for this class
    const int* __restrict__ batches,    // M batch indices (global)
    float* __restrict__ xs,             // LDS [MG][TD]
    float* __restrict__ red,            // LDS [16][16][4]
    int* __restrict__ row_lds)          // LDS [MG]
{
    constexpr int LPR  = R / 4;          // lanes per A-row (16 or 4)
    constexpr int ROWS = BLOCK / LPR;    // A-rows per iter (64 or 256)
    constexpr int IT   = TD / ROWS;      // iters per d-tile (32 or 8)

    const int t = threadIdx.x;
    int rows[M];
#pragma unroll
    for (int m = 0; m < M; ++m) rows[m] = batches[m];
    if (t < M) row_lds[t] = rows[t];

    const int d_sub  = t / LPR;
    const int r_base = (t % LPR) * 4;

    float acc[M][4];
#pragma unroll
    for (int m = 0; m < M; ++m)
#pragma unroll
        for (int j = 0; j < 4; ++j) acc[m][j] = 0.0f;

    for (int dt = 0; dt < NDIM; dt += TD) {
        __syncthreads();   // previous tile/group reads of xs done; row_lds visible
        // stage M x-row tiles: M*TD/4 float4 loads spread over the block
        for (int i = t; i < M * (TD / 4); i += BLOCK) {
            const int m   = i >> 9;        // TD/4 == 512
            const int idx = i & 511;
            reinterpret_cast<float4*>(xs + m * TD)[idx] =
                reinterpret_cast<const float4*>(x + (size_t)row_lds[m] * NDIM + dt)[idx];
        }
        __syncthreads();

        const float* Abt = Ab + (size_t)dt * R;
#pragma unroll 4
        for (int i = 0; i < IT; ++i) {
            const int d = i * ROWS + d_sub;
            const float4 av = *reinterpret_cast<const float4*>(Abt + (size_t)d * R + r_base);
#pragma unroll
            for (int m = 0; m < M; ++m) {
                const float xv = xs[m * TD + d];
                acc[m][0] = fmaf(xv, av.x, acc[m][0]);
                acc[m][1] = fmaf(xv, av.y, acc[m][1]);
                acc[m][2] = fmaf(xv, av.z, acc[m][2]);
                acc[m][3] = fmaf(xv, av.w, acc[m][3]);
            }
        }
    }

    // reduce: shuffle within wave, LDS across 16 waves, one m at a time
    const int wave = t >> 6;
    const int lane = t & 63;
#pragma unroll
    for (int m = 0; m < M; ++m)
#pragma unroll
        for (int off = 32; off >= LPR; off >>= 1)
#pragma unroll
            for (int j = 0; j < 4; ++j)
                acc[m][j] += __shfl_down(acc[m][j], off, 64);

#pragma unroll
    for (int m = 0; m < M; ++m) {
        __syncthreads();
        if (lane < LPR)
#pragma unroll
            for (int j = 0; j < 4; ++j) red[(wave * 16 + lane) * 4 + j] = acc[m][j];
        __syncthreads();
        if (t < R) {
            const int rl = t / 4, j = t % 4;
            float v = 0.0f;
#pragma unroll
            for (int w = 0; w < 16; ++w) v += red[(w * 16 + rl) * 4 + j];
            outb[(size_t)rows[m] * R + t] = v;
        }
    }
}

template<int R>
__device__ __forceinline__ void run_wid(
    const float* x, const float* Ab, float* outb,
    const int* bucket, int count, int half,
    float* xs, float* red, int* row_lds)
{
    // two blocks per wid: block `half` handles groups half, half+2, half+4, ...
    for (int g = half * MG; g < count; g += 2 * MG) {
        const int M = min(MG, count - g);
        const int* b = bucket + g;
        switch (M) {
            case 1: gemv_group<R, 1>(x, Ab, outb, b, xs, red, row_lds); break;
            case 2: gemv_group<R, 2>(x, Ab, outb, b, xs, red, row_lds); break;
            case 3: gemv_group<R, 3>(x, Ab, outb, b, xs, red, row_lds); break;
            default: gemv_group<R, 4>(x, Ab, outb, b, xs, red, row_lds); break;
        }
    }
}

__global__ __launch_bounds__(BLOCK, 8)
void SequentialLoraA_kernel(const float* __restrict__ x,
                            const float* __restrict__ Al,
                            const float* __restrict__ As,
                            float* __restrict__ out,
                            const int* __restrict__ ws)
{
    __shared__ float xs[MG * TD];        // 32 KB
    __shared__ float red[16 * 16 * 4];   // 4 KB
    __shared__ int row_lds[MG];

    const int blk  = blockIdx.x;         // 0..511
    const int half = blk & 1;

    if (blk < 2 * N_WID) {
        const int wid = blk >> 1;
        const int count = ws[WS_CNT_L + wid];
        run_wid<R_LG>(x,
                      Al + (size_t)wid * NDIM * R_LG,
                      out,
                      ws + WS_BKT_L + wid * MAXB, count, half,
                      xs, red, row_lds);
    } else {
        const int wid = (blk - 2 * N_WID) >> 1;
        const int count = ws[WS_CNT_S + wid];
        run_wid<R_SM>(x + (size_t)B_LG * NDIM,
                      As + (size_t)wid * NDIM * R_SM,
                      out + (size_t)B_LG * R_LG,
                      ws + WS_BKT_S + wid * MAXB, count, half,
                      xs, red, row_lds);
    }
}

extern "C" void kernel_launch(void* const* d_in, const int* in_sizes, int n_in,
                              void* d_out, int out_size, void* d_ws, size_t ws_size,
                              hipStream_t stream) {
    const float* x      = (const float*)d_in[0];
    const int*   wids_l = (const int*)d_in[1];
    const int*   wids_s = (const int*)d_in[2];
    const float* Al     = (const float*)d_in[3];
    const float* As     = (const float*)d_in[4];
    float* out = (float*)d_out;
    int*   ws  = (int*)d_ws;

    bucket_kernel<<<1, 256, 0, stream>>>(wids_l, wids_s, ws);
    SequentialLoraA_kernel<<<4 * N_WID, BLOCK, 0, stream>>>(x, Al, As, out, ws);
}

// Round 5
// 228.911 us; speedup vs baseline: 1.0220x; 1.0220x over previous
//
#include <hip/hip_runtime.h>

#define NDIM 4096
#define HALF 2048          // d-rows per block (half of NDIM)
#define B_LG 256
#define B_SM 256
#define N_WID 128
#define R_LG 64
#define R_SM 16
#define BLOCK 1024
#define MAXB 256           // bucket capacity per wid
#define MG 4               // max batches fused per pass over A
#define PF 4               // prefetch depth (float4 loads in flight per thread)
#define OUT_SIZE (B_LG * R_LG + B_SM * R_SM)

// d_ws ints: [0..128) cnt_l | [128..256) cnt_s | buckets
#define WS_CNT_L 0
#define WS_CNT_S 128
#define WS_BKT_L 256
#define WS_BKT_S (256 + N_WID * MAXB)

// ------------- kernel 1: bucket batches by wid + zero out -------------------
__global__ __launch_bounds__(BLOCK)
void setup_kernel(const int* __restrict__ wids_l,
                  const int* __restrict__ wids_s,
                  int* __restrict__ ws,
                  float* __restrict__ out)
{
    __shared__ int cl[N_WID], cs[N_WID];
    const int t = threadIdx.x;
    if (t < N_WID) { cl[t] = 0; cs[t] = 0; }
    __syncthreads();
    if (t < B_LG) {
        const int w = wids_l[t];
        const int s = atomicAdd(&cl[w], 1);
        ws[WS_BKT_L + w * MAXB + s] = t;
    } else if (t < B_LG + B_SM) {
        const int b = t - B_LG;
        const int w = wids_s[b];
        const int s = atomicAdd(&cs[w], 1);
        ws[WS_BKT_S + w * MAXB + s] = b;
    }
    __syncthreads();
    if (t < N_WID) { ws[WS_CNT_L + t] = cl[t]; ws[WS_CNT_S + t] = cs[t]; }
    for (int i = t; i < OUT_SIZE; i += BLOCK) out[i] = 0.0f;
}

// ------------- kernel 2: grouped half-GEMV ----------------------------------
// One block streams HALF d-rows of A[wid] once, accumulating up to M batches'
// partial dots; partials combined across the two halves via atomicAdd.
template<int R, int M>
__device__ __forceinline__ void gemv_half(
    const float* __restrict__ x,      // x rows base for this class
    const float* __restrict__ Ab,     // A[wid]
    float* __restrict__ outb,         // out base for this class
    const int* __restrict__ batches,  // M batch indices (uniform scalar reads)
    int d0,                           // d offset of this half
    float* __restrict__ xs,           // LDS [MG][HALF]
    float* __restrict__ red)          // LDS [16][16][4]
{
    constexpr int LPR  = R / 4;        // lanes per A-row: 16 (R=64) or 4 (R=16)
    constexpr int ROWS = BLOCK / LPR;  // A-rows per float4-iter: 64 or 256
    constexpr int IT   = HALF / ROWS;  // 32 or 8

    const int t = threadIdx.x;

    int rows[M];
#pragma unroll
    for (int m = 0; m < M; ++m) rows[m] = batches[m];  // uniform -> s_load

    __syncthreads();  // previous group's FMA/red reads finished
    // stage M x-row half-tiles (static m -> no dynamic reg indexing)
#pragma unroll
    for (int m = 0; m < M; ++m) {
        if (t < HALF / 4) {
            reinterpret_cast<float4*>(xs + m * HALF)[t] =
                reinterpret_cast<const float4*>(x + (size_t)rows[m] * NDIM + d0)[t];
        }
    }
    __syncthreads();

    const int d_sub  = t / LPR;
    const int r_base = (t % LPR) * 4;
    const float* Abt = Ab + (size_t)d0 * R + r_base;

    float acc[M][4];
#pragma unroll
    for (int m = 0; m < M; ++m)
#pragma unroll
        for (int j = 0; j < 4; ++j) acc[m][j] = 0.0f;

    for (int ig = 0; ig < IT; ig += PF) {
        float4 pf[PF];
#pragma unroll
        for (int p = 0; p < PF; ++p) {
            const int d = (ig + p) * ROWS + d_sub;
            pf[p] = *reinterpret_cast<const float4*>(Abt + (size_t)d * R);
        }
#pragma unroll
        for (int p = 0; p < PF; ++p) {
            const int d = (ig + p) * ROWS + d_sub;
#pragma unroll
            for (int m = 0; m < M; ++m) {
                const float xv = xs[m * HALF + d];
                acc[m][0] = fmaf(xv, pf[p].x, acc[m][0]);
                acc[m][1] = fmaf(xv, pf[p].y, acc[m][1]);
                acc[m][2] = fmaf(xv, pf[p].z, acc[m][2]);
                acc[m][3] = fmaf(xv, pf[p].w, acc[m][3]);
            }
        }
    }

    // reduce: shuffle within wave, LDS across 16 waves, atomicAdd per half
    const int wave = t >> 6;
    const int lane = t & 63;
#pragma unroll
    for (int m = 0; m < M; ++m)
#pragma unroll
        for (int off = 32; off >= LPR; off >>= 1)
#pragma unroll
            for (int j = 0; j < 4; ++j)
                acc[m][j] += __shfl_down(acc[m][j], off, 64);

#pragma unroll
    for (int m = 0; m < M; ++m) {
        __syncthreads();
        if (lane < LPR)
#pragma unroll
            for (int j = 0; j < 4; ++j) red[(wave * 16 + lane) * 4 + j] = acc[m][j];
        __syncthreads();
        if (t < R) {
            const int rl = t / 4, j = t % 4;
            float v = 0.0f;
#pragma unroll
            for (int w = 0; w < 16; ++w) v += red[(w * 16 + rl) * 4 + j];
            atomicAdd(outb + (size_t)rows[m] * R + t, v);
        }
    }
}

template<int R>
__device__ __forceinline__ void run_wid_half(
    const float* x, const float* Ab, float* outb,
    const int* bucket, int count, int d0,
    float* xs, float* red)
{
    for (int g = 0; g < count; g += MG) {
        const int M = min(MG, count - g);
        const int* b = bucket + g;
        switch (M) {
            case 1: gemv_half<R, 1>(x, Ab, outb, b, d0, xs, red); break;
            case 2: gemv_half<R, 2>(x, Ab, outb, b, d0, xs, red); break;
            case 3: gemv_half<R, 3>(x, Ab, outb, b, d0, xs, red); break;
            default: gemv_half<R, 4>(x, Ab, outb, b, d0, xs, red); break;
        }
    }
}

__global__ __launch_bounds__(BLOCK, 4)
void SequentialLoraA_kernel(const float* __restrict__ x,
                            const float* __restrict__ Al,
                            const float* __restrict__ As,
                            float* __restrict__ out,
                            const int* __restrict__ ws)
{
    __shared__ float xs[MG * HALF];      // 32 KB
    __shared__ float red[16 * 16 * 4];   // 4 KB

    const int blk  = blockIdx.x;         // 0..511, all active
    if (blk < 2 * N_WID) {
        const int wid  = blk >> 1;
        const int d0   = (blk & 1) * HALF;
        const int count = ws[WS_CNT_L + wid];
        run_wid_half<R_LG>(x,
                           Al + (size_t)wid * NDIM * R_LG,
                           out,
                           ws + WS_BKT_L + wid * MAXB, count, d0,
                           xs, red);
    } else {
        const int wid  = (blk - 2 * N_WID) >> 1;
        const int d0   = (blk & 1) * HALF;
        const int count = ws[WS_CNT_S + wid];
        run_wid_half<R_SM>(x + (size_t)B_LG * NDIM,
                           As + (size_t)wid * NDIM * R_SM,
                           out + (size_t)B_LG * R_LG,
                           ws + WS_BKT_S + wid * MAXB, count, d0,
                           xs, red);
    }
}

extern "C" void kernel_launch(void* const* d_in, const int* in_sizes, int n_in,
                              void* d_out, int out_size, void* d_ws, size_t ws_size,
                              hipStream_t stream) {
    const float* x      = (const float*)d_in[0];
    const int*   wids_l = (const int*)d_in[1];
    const int*   wids_s = (const int*)d_in[2];
    const float* Al     = (const float*)d_in[3];
    const float* As     = (const float*)d_in[4];
    float* out = (float*)d_out;
    int*   ws  = (int*)d_ws;

    setup_kernel<<<1, BLOCK, 0, stream>>>(wids_l, wids_s, ws, out);
    SequentialLoraA_kernel<<<4 * N_WID, BLOCK, 0, stream>>>(x, Al, As, out, ws);
}